// Round 1
// baseline (957.614 us; speedup 1.0000x reference)
//
#include <hip/hip_runtime.h>

#define IMG_H 512
#define IMG_W 512
#define TX 64
#define TY 64
#define HALO 12               // KY-1 = 12, 6 each side
#define IN_ROWS (TY + HALO)   // 76
#define IN_COLS (TX + HALO)   // 76
#define IN_STRIDE 77          // 77 % 32 = 13, coprime with 32 -> conflict-free
#define HS_STRIDE 65          // 65 % 32 = 1  -> conflict-free

__global__ __launch_bounds__(256) void boxblur_kernel(
    const float* __restrict__ in, const float* __restrict__ kern,
    float* __restrict__ out) {
    __shared__ float in_s[IN_ROWS * IN_STRIDE];  // 76*77*4 = 23408 B
    __shared__ float h_s[IN_ROWS * HS_STRIDE];   // 76*65*4 = 19760 B

    const int tid = threadIdx.x;
    const int x0 = blockIdx.x * TX;
    const int y0 = blockIdx.y * TY;
    const size_t plane = (size_t)blockIdx.z * (IMG_H * IMG_W);
    const float* __restrict__ inp = in + plane;
    float* __restrict__ outp = out + plane;

    // ---- phase 0: load 76x76 haloed tile, reflect at borders ----
    for (int li = tid; li < IN_ROWS * IN_COLS; li += 256) {
        int r = li / IN_COLS;
        int c = li - r * IN_COLS;
        int gy = y0 - 6 + r;
        gy = gy < 0 ? -gy : (gy >= IMG_H ? 2 * IMG_H - 2 - gy : gy);
        int gx = x0 - 6 + c;
        gx = gx < 0 ? -gx : (gx >= IMG_W ? 2 * IMG_W - 2 - gx : gx);
        in_s[r * IN_STRIDE + c] = inp[(size_t)gy * IMG_W + gx];
    }
    __syncthreads();

    // ---- phase 1: horizontal 13-box sliding sums ----
    // tasks: 76 rows x 4 x-segments of 16 outputs = 304 tasks
    for (int task = tid; task < IN_ROWS * 4; task += 256) {
        int r = task % IN_ROWS;       // consecutive lanes -> consecutive rows
        int seg = task / IN_ROWS;
        int xs = seg * 16;
        const float* rowp = &in_s[r * IN_STRIDE];
        float* hrow = &h_s[r * HS_STRIDE];
        // h[r][x] = sum_{c=x..x+12} in_s[r][c]
        float s = 0.f;
        #pragma unroll
        for (int j = 0; j < 13; ++j) s += rowp[xs + j];
        hrow[xs] = s;
        #pragma unroll
        for (int x = 1; x < 16; ++x) {
            s += rowp[xs + x + 12] - rowp[xs + x - 1];
            hrow[xs + x] = s;
        }
    }
    __syncthreads();

    // ---- phase 2: vertical 13-box sliding sums, write out ----
    // threads = 64 cols x 4 segments of 16 rows
    {
        const int col = tid & 63;
        const int seg = tid >> 6;
        const int ys = seg * 16;
        const float scale = kern[0];  // uniform kernel; total scale applied once
        // out local y needs h_s rows y..y+12
        float s = 0.f;
        #pragma unroll
        for (int j = 0; j < 13; ++j) s += h_s[(ys + j) * HS_STRIDE + col];
        outp[(size_t)(y0 + ys) * IMG_W + x0 + col] = s * scale;
        #pragma unroll
        for (int dy = 1; dy < 16; ++dy) {
            int y = ys + dy;
            s += h_s[(y + 12) * HS_STRIDE + col] - h_s[(y - 1) * HS_STRIDE + col];
            outp[(size_t)(y0 + y) * IMG_W + x0 + col] = s * scale;
        }
    }
}

extern "C" void kernel_launch(void* const* d_in, const int* in_sizes, int n_in,
                              void* d_out, int out_size, void* d_ws, size_t ws_size,
                              hipStream_t stream) {
    const float* x = (const float*)d_in[0];
    const float* k = (const float*)d_in[1];
    float* out = (float*)d_out;
    dim3 grid(IMG_W / TX, IMG_H / TY, 8 * 64);  // 8 x-tiles, 8 y-tiles, B*C planes
    dim3 block(256);
    boxblur_kernel<<<grid, block, 0, stream>>>(x, k, out);
}

// Round 2
// 868.629 us; speedup vs baseline: 1.1024x; 1.1024x over previous
//
#include <hip/hip_runtime.h>

#define IMG_H 512
#define IMG_W 512
#define TX 64
#define TY 64
#define VCOLS 76      // TX + 12 halo
#define VSTR 78       // v_s row stride (even: enables b64 merges; banks ok)
#define OSTR 68       // o_s row stride (16B-aligned rows for float4 path)

__global__ __launch_bounds__(256) void boxblur_kernel(
    const float* __restrict__ in, const float* __restrict__ kern,
    float* __restrict__ out) {
    __shared__ float v_s[TY * VSTR];  // 64*78*4 = 19968 B  vertical box sums
    __shared__ float o_s[TY * OSTR];  // 64*68*4 = 17408 B  output tile

    const int tid = threadIdx.x;
    const int x0 = blockIdx.x * TX;
    const int y0 = blockIdx.y * TY;
    const size_t plane = (size_t)blockIdx.z * (size_t)(IMG_H * IMG_W);
    const float* __restrict__ inp = in + plane;

    // ---- phase 1: vertical 13-box sums, global -> v_s (coalesced loads) ----
    // tasks: 76 cols x 4 row-segments of 16 outputs = 304
    for (int task = tid; task < VCOLS * 4; task += 256) {
        int c = task % VCOLS;      // consecutive lanes -> consecutive columns
        int s = task / VCOLS;
        int gx = x0 - 6 + c;
        gx = gx < 0 ? -gx : (gx > IMG_W - 1 ? 2 * (IMG_W - 1) - gx : gx);
        int yb = y0 + s * 16;      // first output row of this segment
        float a[28];
        #pragma unroll
        for (int k = 0; k < 28; ++k) {
            int gy = yb - 6 + k;   // wave-uniform (except seg-straddling waves)
            gy = gy < 0 ? -gy : (gy > IMG_H - 1 ? 2 * (IMG_H - 1) - gy : gy);
            a[k] = inp[(size_t)gy * IMG_W + gx];
        }
        float sum = 0.f;
        #pragma unroll
        for (int k = 0; k < 13; ++k) sum += a[k];
        v_s[(s * 16) * VSTR + c] = sum;
        #pragma unroll
        for (int t = 1; t < 16; ++t) {
            sum += a[t + 12] - a[t - 1];
            v_s[(s * 16 + t) * VSTR + c] = sum;
        }
    }
    __syncthreads();

    // ---- phase 2: horizontal 13-box sliding over v_s -> o_s ----
    // 256 tasks exactly: 64 rows x 4 x-segments of 16
    {
        const int y = tid & 63;
        const int s = tid >> 6;
        const int xb = s * 16;
        const float scale = kern[0];
        const float* vrow = &v_s[y * VSTR + xb];
        float* orow = &o_s[y * OSTR + xb];
        float sum = 0.f;
        #pragma unroll
        for (int j = 0; j < 13; ++j) sum += vrow[j];
        orow[0] = sum * scale;
        #pragma unroll
        for (int t = 1; t < 16; ++t) {
            sum += vrow[t + 12] - vrow[t - 1];
            orow[t] = sum * scale;
        }
    }
    __syncthreads();

    // ---- phase 3: o_s -> out with float4 stores (coalesced) ----
    {
        float* __restrict__ outp = out + plane;
        const int g = tid & 15;        // column group (4 cols)
        const int seg = tid >> 4;      // 16 segs x 4 rows
        #pragma unroll
        for (int i = 0; i < 4; ++i) {
            int r = seg * 4 + i;
            float4 v;
            v.x = o_s[r * OSTR + 4 * g + 0];
            v.y = o_s[r * OSTR + 4 * g + 1];
            v.z = o_s[r * OSTR + 4 * g + 2];
            v.w = o_s[r * OSTR + 4 * g + 3];
            *(float4*)(outp + (size_t)(y0 + r) * IMG_W + x0 + 4 * g) = v;
        }
    }
}

extern "C" void kernel_launch(void* const* d_in, const int* in_sizes, int n_in,
                              void* d_out, int out_size, void* d_ws, size_t ws_size,
                              hipStream_t stream) {
    const float* x = (const float*)d_in[0];
    const float* k = (const float*)d_in[1];
    float* out = (float*)d_out;
    dim3 grid(IMG_W / TX, IMG_H / TY, 8 * 64);  // x-tiles, y-tiles, B*C planes
    dim3 block(256);
    boxblur_kernel<<<grid, block, 0, stream>>>(x, k, out);
}